// Round 12
// baseline (121.627 us; speedup 1.0000x reference)
//
#include <hip/hip_runtime.h>
#include <math.h>

// MLPEMABlock — only the ema_var path survives (both MLP branches are *0 in the ref).
//
// Stage 1 (unchanged, known-good): truncated EMA via prefix subtraction:
//   p[t] = a*p[t-1] + x[t]  (untruncated scan),  n[t] = p[t] - a^201 * p[t-201].
//   Block = one (b,f) row. 256 threads x 32-elem local scan, shfl wave scan,
//   cross-wave combine. LDS prefixes pad-1-per-32 -> stride-33 conflict-free.
// Stage 2 (v3): vt[64][256] in LDS is the ONLY DS traffic; weights/bias/norm_w
//   come in via wave-uniform scalar loads (readfirstlane-pinned k0 -> s_load),
//   norm_w folded into the va operand; thread tile 4t x 16k; float4 stores.

#define SB    8192
#define BB    8
#define FF    64
#define EPSF  1e-8f
#define HALO  201

// ---------------- stage 1 ----------------
#define PAD1(o) ((o) + ((o) >> 5))
#define QLEN (PAD1(SB - 1) + 1)      // 8447 floats

__global__ __launch_bounds__(256) void ema_var_kernel(
    const float* __restrict__ x,            // (B, F, S)
    const float* __restrict__ log_hl_var,   // (F)
    float* __restrict__ var_out)            // (B, F, S) in d_ws
{
  __shared__ float qx [QLEN];
  __shared__ float qx2[QLEN];
  __shared__ float wcx[4], wcx2[4];

  const int tid  = threadIdx.x;
  const int lane = tid & 63;
  const int w    = tid >> 6;
  const int bf   = blockIdx.x;        // 0..511
  const int b    = bf >> 6;
  const int f    = bf & 63;

  const float hl     = expf(log_hl_var[f]);
  const float invhl  = 1.0f / hl;
  const float alpha  = exp2f(-invhl);            // 0.5^(1/hl)
  const float a201   = exp2f(-201.0f * invhl);
  const float inv1ma = 1.0f / (1.0f - alpha);
  const float rd_st  = 1.0f / ((1.0f - a201) * inv1ma + EPSF);
  const float m32    = exp2f(-32.0f * invhl);    // alpha^32
  const float m2048  = exp2f(-2048.0f * invhl);  // alpha^2048 (per-wave span)

  const float* __restrict__ xp = x + (long)(b * FF + f) * SB;
  const int t0 = tid * 32;

  // ---- load own 32 x values (global -> regs, dense across the wave)
  float qa[32];
  float q2[32];
#pragma unroll
  for (int g = 0; g < 8; ++g) {
    const float4 v4 = *(const float4*)&xp[t0 + g * 4];
    qa[g*4+0] = v4.x; qa[g*4+1] = v4.y; qa[g*4+2] = v4.z; qa[g*4+3] = v4.w;
  }

  // ---- local scans: s = a*s + x ; s2 = a*s2 + x*x
  {
    float sx = 0.f, sx2 = 0.f;
#pragma unroll
    for (int j = 0; j < 32; ++j) {
      const float xv = qa[j];
      sx  = fmaf(alpha, sx,  xv);
      sx2 = fmaf(alpha, sx2, xv * xv);
      qa[j] = sx;
      q2[j] = sx2;
    }
  }

  // ---- wave scan of chunk carries with uniform factor m32
  float bx = qa[31], bx2 = q2[31];
  {
    float p = m32;
#pragma unroll
    for (int off = 1; off < 64; off <<= 1) {
      const float ux  = __shfl_up(bx,  off, 64);
      const float ux2 = __shfl_up(bx2, off, 64);
      if (lane >= off) { bx = fmaf(p, ux, bx); bx2 = fmaf(p, ux2, bx2); }
      p *= p;
    }
  }
  if (lane == 63) { wcx[w] = bx; wcx2[w] = bx2; }
  __syncthreads();

  // ---- block carry-in for this wave (serial over <=3 wave carries)
  float ax = 0.f, ax2 = 0.f;
  for (int i = 0; i < w; ++i) {
    ax  = fmaf(m2048, ax,  wcx[i]);
    ax2 = fmaf(m2048, ax2, wcx2[i]);
  }

  // ---- C_{tid-1}: prefix state just before this thread's chunk
  const float bux  = __shfl_up(bx,  1, 64);
  const float bux2 = __shfl_up(bx2, 1, 64);
  const float powl = exp2f(-32.0f * (float)lane * invhl);   // m32^lane
  float Cx, Cx2;
  if (lane == 0) { Cx = ax;                  Cx2 = ax2; }
  else           { Cx = fmaf(powl, ax, bux); Cx2 = fmaf(powl, ax2, bux2); }

  // ---- apply carry, keep q in regs, publish to LDS (stride-33: conflict-free)
  {
    float pf = alpha;
    const int base = 33 * tid;          // == PAD1(32*tid) .. contiguous 32
#pragma unroll
    for (int j = 0; j < 32; ++j) {
      const float qv  = fmaf(pf, Cx,  qa[j]);
      const float qv2 = fmaf(pf, Cx2, q2[j]);
      qa[j] = qv;  q2[j] = qv2;
      qx [base + j] = qv;
      qx2[base + j] = qv2;
      pf *= alpha;
    }
  }
  __syncthreads();

  // ---- n[t] = q[t] - a201*q[t-201]; var = E[x2] - E[x]^2
  float vr[32];
#pragma unroll
  for (int j = 0; j < 32; ++j) {
    const int t = t0 + j;
    float nqx = qa[j], nqx2 = q2[j];
    if (t >= HALO) {
      const int po = PAD1(t - HALO);    // stride-33 across lanes: conflict-free
      nqx  = fmaf(-a201, qx [po], nqx);
      nqx2 = fmaf(-a201, qx2[po], nqx2);
    }
    float rd = rd_st;
    if (t < 200) {                      // short window: den=(1-a^(t+1))/(1-a)
      rd = 1.0f / ((1.0f - exp2f(-(float)(t + 1) * invhl)) * inv1ma + EPSF);
    }
    const float m1 = nqx * rd;
    vr[j] = fmaf(nqx2, rd, -(m1 * m1));
  }
  __syncthreads();                      // all shifted reads done before overwrite

  // ---- stage var into qx (own chunk), then coalesced float4 stores
  {
    const int base = 33 * tid;
#pragma unroll
    for (int j = 0; j < 32; ++j) qx[base + j] = vr[j];
  }
  __syncthreads();

  float* __restrict__ vp = var_out + (long)(b * FF + f) * SB;
#pragma unroll
  for (int g = 0; g < 8; ++g) {
    const int i = (g * 256 + tid) * 4;  // consecutive across threads
    float4 v4;
    v4.x = qx[PAD1(i + 0)];
    v4.y = qx[PAD1(i + 1)];
    v4.z = qx[PAD1(i + 2)];
    v4.w = qx[PAD1(i + 3)];
    *(float4*)&vp[i] = v4;
  }
}

// ---------------- stage 2 (v3: scalar-path weights, vt-only LDS) ----------------
#define RT 256    // rows (t) per block

__global__ __launch_bounds__(512, 2) void stage2_kernel(
    const float* __restrict__ var,      // (B, F, S) from d_ws
    const float* __restrict__ norm_w,   // (192)
    const float* __restrict__ lin_W,    // (192, 128) row-major
    const float* __restrict__ lin_b,    // (128)
    float* __restrict__ out)            // output (B,64,S) then skip (B,64,S)
{
  __shared__ float vt[FF * RT];         // 64 KB  vt[f*256 + t]  (raw var values)
  __shared__ float invl[RT];

  const int tid = threadIdx.x;
  const int b   = blockIdx.x >> 5;           // 32 blocks per batch (8192/256)
  const int t0  = (blockIdx.x & 31) * RT;

  const int lane = tid & 63;
  const int w    = tid >> 6;                 // wave 0..7 = k-slice

  // --- load vt: one f-row (256 floats = 64 lanes x float4) per wave per iter
  {
    const float* __restrict__ vbase = var + (long)(b * FF) * SB + t0;
#pragma unroll
    for (int f = w; f < FF; f += 8) {
      float4 v4 = *(const float4*)&vbase[(long)f * SB + lane * 4];
      *(float4*)&vt[f * RT + lane * 4] = v4;
    }
  }
  __syncthreads();

  // --- rms pass: thread t (tid<256) sums 64 f; 128 of 192 ref channels are zero
  if (tid < RT) {
    float ss = 0.f;
#pragma unroll
    for (int f = 0; f < FF; ++f) {
      const float v = vt[f * RT + tid];
      ss = fmaf(v, v, ss);
    }
    invl[tid] = 1.0f / sqrtf(fmaf(ss, (1.0f / 192.0f), EPSF));
  }
  __syncthreads();

  // --- GEMM: thread tile 4t x 16k; k = k0 + kk; t = tt*4 + j
  const int tt = lane;                        // 0..63 -> 4 t each (covers 256)
  // pin k0 to an SGPR so all weight/bias addresses are provably wave-uniform
  const int k0 = __builtin_amdgcn_readfirstlane(w * 16);

  const float* __restrict__ wbase = lin_W + 128 * 128 + k0;   // rows 128..191
  const float* __restrict__ nwb   = norm_w + 128;

  float acc[4][16];
#pragma unroll
  for (int j = 0; j < 4; ++j)
#pragma unroll
    for (int kk = 0; kk < 16; ++kk) acc[j][kk] = 0.f;

  for (int f = 0; f < FF; ++f) {
    const float4 va = *(const float4*)&vt[f * RT + tt * 4];   // only DS op/iter
    const float nwf = nwb[f];                                 // uniform s_load
    // weights: uniform address -> scalar loads on the SMEM pipe (no DS, no VMEM)
    const float4 w0 = *(const float4*)&wbase[f * 128 + 0];
    const float4 w1 = *(const float4*)&wbase[f * 128 + 4];
    const float4 w2 = *(const float4*)&wbase[f * 128 + 8];
    const float4 w3 = *(const float4*)&wbase[f * 128 + 12];
    const float wv[16] = { w0.x, w0.y, w0.z, w0.w, w1.x, w1.y, w1.z, w1.w,
                           w2.x, w2.y, w2.z, w2.w, w3.x, w3.y, w3.z, w3.w };
    const float vv[4] = { va.x * nwf, va.y * nwf, va.z * nwf, va.w * nwf };
#pragma unroll
    for (int j = 0; j < 4; ++j)
#pragma unroll
      for (int kk = 0; kk < 16; ++kk)
        acc[j][kk] = fmaf(vv[j], wv[kk], acc[j][kk]);
  }

  // --- epilogue: res = acc*inv[t] + b[k]; float4 coalesced stores
  const float4 inv4 = *(const float4*)&invl[tt * 4];
  const float iv[4] = { inv4.x, inv4.y, inv4.z, inv4.w };
  const long skip_base = (long)BB * 64 * SB;    // out = [output | skip]

#pragma unroll
  for (int kk = 0; kk < 16; ++kk) {
    const int k = k0 + kk;
    const float bk = lin_b[k];                  // uniform s_load
    float4 r;
    r.x = fmaf(acc[0][kk], iv[0], bk);
    r.y = fmaf(acc[1][kk], iv[1], bk);
    r.z = fmaf(acc[2][kk], iv[2], bk);
    r.w = fmaf(acc[3][kk], iv[3], bk);
    const long dst = (k < 64)
        ? (skip_base + ((long)(b * 64 + k)) * SB + t0 + tt * 4)       // skip_y
        : (((long)(b * 64 + (k - 64))) * SB + t0 + tt * 4);           // output
    *(float4*)&out[dst] = r;
  }
}

extern "C" void kernel_launch(void* const* d_in, const int* in_sizes, int n_in,
                              void* d_out, int out_size, void* d_ws, size_t ws_size,
                              hipStream_t stream) {
  // 0:x 1:log_hl_in 2:log_hl_out 3:log_hl_var 4:W1 5:b1 6:W2 7:b2 8:norm_w 9:lin_W 10:lin_b
  const float* x          = (const float*)d_in[0];
  const float* log_hl_var = (const float*)d_in[3];
  const float* norm_w     = (const float*)d_in[8];
  const float* lin_W      = (const float*)d_in[9];
  const float* lin_b      = (const float*)d_in[10];
  float* var_ws = (float*)d_ws;               // B*F*S*4 = 16 MiB scratch
  float* out    = (float*)d_out;

  ema_var_kernel<<<dim3(BB * FF), dim3(256), 0, stream>>>(x, log_hl_var, var_ws);
  stage2_kernel<<<dim3(BB * (SB / RT)), dim3(512), 0, stream>>>(
      var_ws, norm_w, lin_W, lin_b, out);
}

// Round 13
// 117.064 us; speedup vs baseline: 1.0390x; 1.0390x over previous
//
#include <hip/hip_runtime.h>
#include <math.h>

// MLPEMABlock — only the ema_var path survives (both MLP branches are *0 in the ref).
//
// Stage 1 (unchanged, known-good): truncated EMA via prefix subtraction.
// Stage 2 (v4): latency-hiding fix. RT=128, 512 threads, grid 512 -> 2 blocks/CU,
//   4 waves/SIMD (was 2). Thread tile 2t x 16k. vt[64][128] (32 KB) in LDS; rms
//   split over all 8 waves; weights/bias/norm_w via wave-uniform global loads.

#define SB    8192
#define BB    8
#define FF    64
#define EPSF  1e-8f
#define HALO  201

// ---------------- stage 1 ----------------
#define PAD1(o) ((o) + ((o) >> 5))
#define QLEN (PAD1(SB - 1) + 1)      // 8447 floats

__global__ __launch_bounds__(256) void ema_var_kernel(
    const float* __restrict__ x,            // (B, F, S)
    const float* __restrict__ log_hl_var,   // (F)
    float* __restrict__ var_out)            // (B, F, S) in d_ws
{
  __shared__ float qx [QLEN];
  __shared__ float qx2[QLEN];
  __shared__ float wcx[4], wcx2[4];

  const int tid  = threadIdx.x;
  const int lane = tid & 63;
  const int w    = tid >> 6;
  const int bf   = blockIdx.x;        // 0..511
  const int b    = bf >> 6;
  const int f    = bf & 63;

  const float hl     = expf(log_hl_var[f]);
  const float invhl  = 1.0f / hl;
  const float alpha  = exp2f(-invhl);            // 0.5^(1/hl)
  const float a201   = exp2f(-201.0f * invhl);
  const float inv1ma = 1.0f / (1.0f - alpha);
  const float rd_st  = 1.0f / ((1.0f - a201) * inv1ma + EPSF);
  const float m32    = exp2f(-32.0f * invhl);    // alpha^32
  const float m2048  = exp2f(-2048.0f * invhl);  // alpha^2048 (per-wave span)

  const float* __restrict__ xp = x + (long)(b * FF + f) * SB;
  const int t0 = tid * 32;

  // ---- load own 32 x values (global -> regs, dense across the wave)
  float qa[32];
  float q2[32];
#pragma unroll
  for (int g = 0; g < 8; ++g) {
    const float4 v4 = *(const float4*)&xp[t0 + g * 4];
    qa[g*4+0] = v4.x; qa[g*4+1] = v4.y; qa[g*4+2] = v4.z; qa[g*4+3] = v4.w;
  }

  // ---- local scans: s = a*s + x ; s2 = a*s2 + x*x
  {
    float sx = 0.f, sx2 = 0.f;
#pragma unroll
    for (int j = 0; j < 32; ++j) {
      const float xv = qa[j];
      sx  = fmaf(alpha, sx,  xv);
      sx2 = fmaf(alpha, sx2, xv * xv);
      qa[j] = sx;
      q2[j] = sx2;
    }
  }

  // ---- wave scan of chunk carries with uniform factor m32
  float bx = qa[31], bx2 = q2[31];
  {
    float p = m32;
#pragma unroll
    for (int off = 1; off < 64; off <<= 1) {
      const float ux  = __shfl_up(bx,  off, 64);
      const float ux2 = __shfl_up(bx2, off, 64);
      if (lane >= off) { bx = fmaf(p, ux, bx); bx2 = fmaf(p, ux2, bx2); }
      p *= p;
    }
  }
  if (lane == 63) { wcx[w] = bx; wcx2[w] = bx2; }
  __syncthreads();

  // ---- block carry-in for this wave (serial over <=3 wave carries)
  float ax = 0.f, ax2 = 0.f;
  for (int i = 0; i < w; ++i) {
    ax  = fmaf(m2048, ax,  wcx[i]);
    ax2 = fmaf(m2048, ax2, wcx2[i]);
  }

  // ---- C_{tid-1}: prefix state just before this thread's chunk
  const float bux  = __shfl_up(bx,  1, 64);
  const float bux2 = __shfl_up(bx2, 1, 64);
  const float powl = exp2f(-32.0f * (float)lane * invhl);   // m32^lane
  float Cx, Cx2;
  if (lane == 0) { Cx = ax;                  Cx2 = ax2; }
  else           { Cx = fmaf(powl, ax, bux); Cx2 = fmaf(powl, ax2, bux2); }

  // ---- apply carry, keep q in regs, publish to LDS (stride-33: conflict-free)
  {
    float pf = alpha;
    const int base = 33 * tid;          // == PAD1(32*tid) .. contiguous 32
#pragma unroll
    for (int j = 0; j < 32; ++j) {
      const float qv  = fmaf(pf, Cx,  qa[j]);
      const float qv2 = fmaf(pf, Cx2, q2[j]);
      qa[j] = qv;  q2[j] = qv2;
      qx [base + j] = qv;
      qx2[base + j] = qv2;
      pf *= alpha;
    }
  }
  __syncthreads();

  // ---- n[t] = q[t] - a201*q[t-201]; var = E[x2] - E[x]^2
  float vr[32];
#pragma unroll
  for (int j = 0; j < 32; ++j) {
    const int t = t0 + j;
    float nqx = qa[j], nqx2 = q2[j];
    if (t >= HALO) {
      const int po = PAD1(t - HALO);    // stride-33 across lanes: conflict-free
      nqx  = fmaf(-a201, qx [po], nqx);
      nqx2 = fmaf(-a201, qx2[po], nqx2);
    }
    float rd = rd_st;
    if (t < 200) {                      // short window: den=(1-a^(t+1))/(1-a)
      rd = 1.0f / ((1.0f - exp2f(-(float)(t + 1) * invhl)) * inv1ma + EPSF);
    }
    const float m1 = nqx * rd;
    vr[j] = fmaf(nqx2, rd, -(m1 * m1));
  }
  __syncthreads();                      // all shifted reads done before overwrite

  // ---- stage var into qx (own chunk), then coalesced float4 stores
  {
    const int base = 33 * tid;
#pragma unroll
    for (int j = 0; j < 32; ++j) qx[base + j] = vr[j];
  }
  __syncthreads();

  float* __restrict__ vp = var_out + (long)(b * FF + f) * SB;
#pragma unroll
  for (int g = 0; g < 8; ++g) {
    const int i = (g * 256 + tid) * 4;  // consecutive across threads
    float4 v4;
    v4.x = qx[PAD1(i + 0)];
    v4.y = qx[PAD1(i + 1)];
    v4.z = qx[PAD1(i + 2)];
    v4.w = qx[PAD1(i + 3)];
    *(float4*)&vp[i] = v4;
  }
}

// ---------------- stage 2 (v4: RT=128, 2 blocks/CU, 4 waves/SIMD) ----------------
#define RT 128    // rows (t) per block

__global__ __launch_bounds__(512, 4) void stage2_kernel(
    const float* __restrict__ var,      // (B, F, S) from d_ws
    const float* __restrict__ norm_w,   // (192)
    const float* __restrict__ lin_W,    // (192, 128) row-major
    const float* __restrict__ lin_b,    // (128)
    float* __restrict__ out)            // output (B,64,S) then skip (B,64,S)
{
  __shared__ float vt[FF * RT];         // 32 KB  vt[f*128 + t]
  __shared__ float part[4 * RT];        // 2 KB   partial sums for rms
  __shared__ float invl[RT];

  const int tid = threadIdx.x;
  const int b   = blockIdx.x >> 6;           // 64 blocks per batch (8192/128)
  const int t0g = (blockIdx.x & 63) * RT;

  const int lane = tid & 63;
  const int w    = tid >> 6;                 // wave 0..7 = k-slice

  // --- load vt: 2048 float4 total, 4 per thread; coalesced within f-rows
  {
    const float* __restrict__ vbase = var + (long)(b * FF) * SB + t0g;
#pragma unroll
    for (int s = 0; s < 4; ++s) {
      const int fi = s * 512 + tid;          // float4 index
      const int f  = fi >> 5;                // 32 float4 per 128-row
      const int c  = (fi & 31) * 4;
      float4 v4 = *(const float4*)&vbase[(long)f * SB + c];
      *(float4*)&vt[f * RT + c] = v4;
    }
  }
  __syncthreads();

  // --- rms: t = tid&127, f-group = tid>>7 sums 16 f; then 4-way combine
  {
    const int t  = tid & 127;
    const int fg = tid >> 7;                 // 0..3
    float ss = 0.f;
#pragma unroll
    for (int f = fg * 16; f < fg * 16 + 16; ++f) {
      const float v = vt[f * RT + t];
      ss = fmaf(v, v, ss);
    }
    part[fg * RT + t] = ss;
  }
  __syncthreads();
  if (tid < RT) {
    const float ss = part[tid] + part[RT + tid] + part[2 * RT + tid] + part[3 * RT + tid];
    invl[tid] = 1.0f / sqrtf(fmaf(ss, (1.0f / 192.0f), EPSF));
  }
  __syncthreads();

  // --- GEMM: thread tile 2t x 16k; t0 = lane*2, k = k0 + kk
  const int t0 = lane * 2;
  const int k0 = __builtin_amdgcn_readfirstlane(w * 16);

  const float* __restrict__ wbase = lin_W + 128 * 128 + k0;   // rows 128..191
  const float* __restrict__ nwb   = norm_w + 128;

  float acc0[16], acc1[16];
#pragma unroll
  for (int kk = 0; kk < 16; ++kk) { acc0[kk] = 0.f; acc1[kk] = 0.f; }

  for (int f = 0; f < FF; ++f) {
    const float2 va = *(const float2*)&vt[f * RT + t0];       // 2-way bank alias: free
    const float nwf = nwb[f];                                 // uniform
    const float4 w0 = *(const float4*)&wbase[f * 128 + 0];    // wave-uniform loads
    const float4 w1 = *(const float4*)&wbase[f * 128 + 4];
    const float4 w2 = *(const float4*)&wbase[f * 128 + 8];
    const float4 w3 = *(const float4*)&wbase[f * 128 + 12];
    const float wv[16] = { w0.x, w0.y, w0.z, w0.w, w1.x, w1.y, w1.z, w1.w,
                           w2.x, w2.y, w2.z, w2.w, w3.x, w3.y, w3.z, w3.w };
    const float vv0 = va.x * nwf;
    const float vv1 = va.y * nwf;
#pragma unroll
    for (int kk = 0; kk < 16; ++kk) {
      acc0[kk] = fmaf(vv0, wv[kk], acc0[kk]);
      acc1[kk] = fmaf(vv1, wv[kk], acc1[kk]);
    }
  }

  // --- epilogue: res = acc*inv[t] + b[k]; float2 coalesced stores
  const float iv0 = invl[t0];
  const float iv1 = invl[t0 + 1];
  const long skip_base = (long)BB * 64 * SB;    // out = [output | skip]

#pragma unroll
  for (int kk = 0; kk < 16; ++kk) {
    const int k = k0 + kk;
    const float bk = lin_b[k];                  // uniform
    float2 r;
    r.x = fmaf(acc0[kk], iv0, bk);
    r.y = fmaf(acc1[kk], iv1, bk);
    const long dst = (k < 64)
        ? (skip_base + ((long)(b * 64 + k)) * SB + t0g + t0)          // skip_y
        : (((long)(b * 64 + (k - 64))) * SB + t0g + t0);              // output
    *(float2*)&out[dst] = r;
  }
}

extern "C" void kernel_launch(void* const* d_in, const int* in_sizes, int n_in,
                              void* d_out, int out_size, void* d_ws, size_t ws_size,
                              hipStream_t stream) {
  // 0:x 1:log_hl_in 2:log_hl_out 3:log_hl_var 4:W1 5:b1 6:W2 7:b2 8:norm_w 9:lin_W 10:lin_b
  const float* x          = (const float*)d_in[0];
  const float* log_hl_var = (const float*)d_in[3];
  const float* norm_w     = (const float*)d_in[8];
  const float* lin_W      = (const float*)d_in[9];
  const float* lin_b      = (const float*)d_in[10];
  float* var_ws = (float*)d_ws;               // B*F*S*4 = 16 MiB scratch
  float* out    = (float*)d_out;

  ema_var_kernel<<<dim3(BB * FF), dim3(256), 0, stream>>>(x, log_hl_var, var_ws);
  stage2_kernel<<<dim3(BB * (SB / RT)), dim3(512), 0, stream>>>(
      var_ws, norm_w, lin_W, lin_b, out);
}